// Round 4
// baseline (680.910 us; speedup 1.0000x reference)
//
#include <hip/hip_runtime.h>

typedef unsigned short u16;
typedef __bf16 bf16x8 __attribute__((ext_vector_type(8)));
typedef float f32x4 __attribute__((ext_vector_type(4)));

#define NQ 16384       // queries (8*2048)
#define NC 16384       // codes
#define DD 256         // embed dim
#define BM 128         // block tile M (queries)
#define BN 256         // block tile N (codes)
#define BK 32          // k-step
#define NSPLIT 2
#define NPART (NSPLIT * 2)            // 4: per-(split, wn) partials
#define NTILES ((NC / NSPLIT) / BN)   // 32
#define NSTEPS (NTILES * 8)           // 256 flattened (nt, kc) steps

// ---------- fp32 -> bf16 hi/lo split (RNE) ----------
__device__ __forceinline__ u16 f2bf(float x) {
  unsigned u = __float_as_uint(x);
  u += 0x7fffu + ((u >> 16) & 1u);
  return (u16)(u >> 16);
}
__device__ __forceinline__ float bf2f(u16 h) {
  return __uint_as_float(((unsigned)h) << 16);
}

// async global->LDS, 16B per lane; LDS dest is wave-uniform base + lane*16
__device__ __forceinline__ void gl2lds16(const void* g, void* l) {
  __builtin_amdgcn_global_load_lds((__attribute__((address_space(1))) void*)g,
                                   (__attribute__((address_space(3))) void*)l,
                                   16, 0, 0);
}

// ---------- K0: split z into bf16 hi/lo ----------
__global__ __launch_bounds__(256) void split_z_kernel(const float* __restrict__ z,
                                                      u16* __restrict__ Ah,
                                                      u16* __restrict__ Al) {
  size_t i = (size_t)blockIdx.x * 256 + threadIdx.x;   // float4 index
  float4 v = ((const float4*)z)[i];
  float f[4] = {v.x, v.y, v.z, v.w};
  u16 hh[4], ll[4];
#pragma unroll
  for (int j = 0; j < 4; ++j) {
    hh[j] = f2bf(f[j]);
    ll[j] = f2bf(f[j] - bf2f(hh[j]));
  }
  ushort4 h; h.x = hh[0]; h.y = hh[1]; h.z = hh[2]; h.w = hh[3];
  ushort4 l; l.x = ll[0]; l.y = ll[1]; l.z = ll[2]; l.w = ll[3];
  ((ushort4*)Ah)[i] = h;
  ((ushort4*)Al)[i] = l;
}

// ---------- K0b: row norms in EXACT numpy pairwise order ----------
// np.sum(x*x) len-256: two 128-halves; each half: 8 accumulators
// r[j] = sum_{i step 8} x[i+j]^2, combined ((r0+r1)+(r2+r3))+((r4+r5)+(r6+r7));
// total = half0 + half1. Here j -> lane (8 lanes per row, coalesced 32B loads),
// tree combine via shfl_xor in the identical order. Bitwise == old kernel.
__global__ __launch_bounds__(256) void norm256_kernel(const float* __restrict__ x,
                                                      float* __restrict__ nrm) {
  const int t = threadIdx.x;
  const int j = t & 7;                    // accumulator index within row
  const int row = blockIdx.x * 32 + (t >> 3);
  const float* q = x + (size_t)row * 256;
  float half[2];
#pragma unroll
  for (int h = 0; h < 2; ++h) {
    const float* p = q + h * 128;
    float v0 = p[j];
    float r = __fmul_rn(v0, v0);
#pragma unroll
    for (int i = 8; i < 128; i += 8) {
      float v = p[i + j];
      r = __fadd_rn(r, __fmul_rn(v, v));
    }
    float s1 = __fadd_rn(r, __shfl_xor(r, 1));    // r0+r1 | r2+r3 | ...
    float s2 = __fadd_rn(s1, __shfl_xor(s1, 2));  // (r0+r1)+(r2+r3) | ...
    half[h] = __fadd_rn(s2, __shfl_xor(s2, 4));   // full 8-way, np tree order
  }
  if (j == 0) nrm[row] = __fadd_rn(half[0], half[1]);
}

// ---------- K1: qc = cb @ W^T + bias  (fp32, 64x64 tiles) ----------
// DO NOT change numerics here: dist rounding grid depends on qc bits, and this
// exact configuration produced zero index flips vs the np reference.
__global__ __launch_bounds__(256) void qc_gemm_kernel(const float* __restrict__ cb,
                                                      const float* __restrict__ W,
                                                      const float* __restrict__ bias,
                                                      float* __restrict__ qc) {
  __shared__ float As[64][33];
  __shared__ float Bs[64][33];
  const int bm = blockIdx.x >> 2;   // 256 row tiles
  const int bn = blockIdx.x & 3;    // 4 col tiles
  const int m0 = bm * 64, n0 = bn * 64;
  const int t = threadIdx.x;
  const int tx = t & 15, ty = t >> 4;
  float acc[4][4] = {};
  for (int kc = 0; kc < 256; kc += 32) {
    __syncthreads();
#pragma unroll
    for (int j = 0; j < 8; ++j) {
      int idx = j * 256 + t;            // 0..2047
      int r = idx >> 5, c = idx & 31;
      As[r][c] = cb[(size_t)(m0 + r) * 256 + kc + c];
      Bs[r][c] = W[(size_t)(n0 + r) * 256 + kc + c];
    }
    __syncthreads();
#pragma unroll
    for (int kk = 0; kk < 32; ++kk) {
      float a[4], b[4];
#pragma unroll
      for (int u = 0; u < 4; ++u) a[u] = As[ty * 4 + u][kk];
#pragma unroll
      for (int v = 0; v < 4; ++v) b[v] = Bs[tx * 4 + v][kk];
#pragma unroll
      for (int u = 0; u < 4; ++u)
#pragma unroll
        for (int v = 0; v < 4; ++v) acc[u][v] += a[u] * b[v];
    }
  }
#pragma unroll
  for (int u = 0; u < 4; ++u)
#pragma unroll
    for (int v = 0; v < 4; ++v) {
      int r = m0 + ty * 4 + u, c = n0 + tx * 4 + v;
      qc[(size_t)r * 256 + c] = acc[u][v] + bias[c];
    }
}

// ---------- K1b: per-row bf16 hi/lo split of qc ----------
__global__ __launch_bounds__(256) void split_qc_kernel(const float* __restrict__ qc,
                                                       u16* __restrict__ Bh,
                                                       u16* __restrict__ Bl) {
  size_t i = (size_t)blockIdx.x * 256 + threadIdx.x;   // float4 index
  float4 v = ((const float4*)qc)[i];
  float f[4] = {v.x, v.y, v.z, v.w};
  u16 hh[4], ll[4];
#pragma unroll
  for (int j = 0; j < 4; ++j) {
    hh[j] = f2bf(f[j]);
    ll[j] = f2bf(f[j] - bf2f(hh[j]));
  }
  ushort4 h; h.x = hh[0]; h.y = hh[1]; h.z = hh[2]; h.w = hh[3];
  ushort4 l; l.x = ll[0]; l.y = ll[1]; l.z = ll[2]; l.w = ll[3];
  ((ushort4*)Bh)[i] = h;
  ((ushort4*)Bl)[i] = l;
}

// ---------- K2: fused split-bf16 distance GEMM + argmin ----------
// STRUCTURE (round 4): 2-phase double-buffered pipeline (catalog T3-minimum).
// The 2-barrier-per-kstep structure capped at ~43-50% MfmaUtil (measured
// 7975 cyc/kstep vs 3725 cyc MFMA demand: the gap is the vmcnt(0) barrier
// drain). Now: flatten (nt,kc) into 256 steps; stage step s+1 into buf[cur^1]
// BEFORE computing step s from buf[cur]; ONE __syncthreads() per step. The
// barrier's vmcnt(0) drains loads issued a full MFMA phase (~1900 cyc) ago
// -> near-zero wait. Single barrier is sufficient: stage writes buf[cur^1]
// while reads hit buf[cur]; the end-of-step barrier completes staging AND
// retires reads before that buffer is overwritten two steps later.
// OCCUPANCY: LDS 96 KB -> 1 block/CU -> 1 wave/SIMD -> 512-reg budget:
// acc 128 (AGPR) + frags 96 + rmin/ridx 32 + addr ~30 fits with NO spill
// (rounds 1-3 spilled 113/212/40 MB under the 256-reg cap).
// MFMA ISSUE: passes reordered (all hh, all hl, all lh) so same-acc
// dependent MFMAs are separated by 31 independent ones -- needed at 1
// wave/SIMD. Per-acc accumulation order is STILL hh->hl->lh over ascending
// k-chunks -> bitwise-identical results. Epilogue ops, tie-break, scan
// order unchanged.
//
// LDS rows are 32 elems = 4 chunks of 16B. XOR swizzle: position p of row r
// holds logical chunk p ^ ((r>>1)&3). Staging permutes the per-lane GLOBAL
// address (global_load_lds dest must stay linear); reads apply the same XOR.
// 8 lanes per 16B-granule, uniform over all 32 banks = conflict-free
// (measured 0 in rounds 0-3).
__global__ __launch_bounds__(256, 1) void vq_argmin_kernel(
    const u16* __restrict__ Ah, const u16* __restrict__ Al,
    const u16* __restrict__ Bh, const u16* __restrict__ Bl,
    const float* __restrict__ cnorm, const float* __restrict__ znorm,
    float* __restrict__ pval, int* __restrict__ pidx) {
  __shared__ __align__(16) u16 Ahs[2][BM * BK];   // 2 x  8 KiB
  __shared__ __align__(16) u16 Als[2][BM * BK];   // 2 x  8 KiB
  __shared__ __align__(16) u16 Bhs[2][BN * BK];   // 2 x 16 KiB
  __shared__ __align__(16) u16 Bls[2][BN * BK];   // 2 x 16 KiB  => 96 KiB

  const int bm = blockIdx.x / NSPLIT;
  const int spl = blockIdx.x % NSPLIT;
  const int lane = threadIdx.x & 63;
  const int wid = threadIdx.x >> 6;
  const int wm = wid >> 1, wn = wid & 1;     // 2x2 wave grid, 64x128 each
  const int l15 = lane & 15;
  const int lg = lane >> 4;                  // 0..3
  const int m0 = bm * BM;
  const int ns0 = spl * (NC / NSPLIT);

  // staging: lane covers (row = sweep*16 + (lane>>2), lds chunk = lane&3);
  // global k-chunk = (lane&3) ^ s(r) with s(r) = (r>>1)&3 = (lane>>3)&3
  const int st_r = lane >> 2;                               // row within 16-row sweep
  const int st_k = (((lane & 3) ^ ((lane >> 3) & 3)) << 3); // SWIZZLED k elem offset

  // read side: logical chunk lg lives at position lg ^ ((l15>>1)&3)
  const int rd_sw = ((lg ^ ((l15 >> 1) & 3)) << 3);         // elem offset within row

  // stage flattened step s into buffer buf (nt = s>>3, kc = (s&7)*BK)
  auto stage = [&](int buf, int s) {
    const int ntt = s >> 3;
    const int kcc = (s & 7) * BK;
    const int nn0 = ns0 + ntt * BN;
    // A: 128 rows = 8 sweeps of 16 rows (1024B each); 2 per wave
#pragma unroll
    for (int j = 0; j < 2; ++j) {
      const int grp = wid * 2 + j;               // 0..7
      const int r = grp * 16 + st_r;             // 0..127
      const size_t ga = (size_t)(m0 + r) * DD + kcc + st_k;
      gl2lds16(Ah + ga, &Ahs[buf][grp * 512]);
      gl2lds16(Al + ga, &Als[buf][grp * 512]);
    }
    // B: 256 rows = 16 sweeps; 4 per wave
#pragma unroll
    for (int j = 0; j < 4; ++j) {
      const int grp = wid * 4 + j;               // 0..15
      const int r = grp * 16 + st_r;             // 0..255
      const size_t gb = (size_t)(nn0 + r) * DD + kcc + st_k;
      gl2lds16(Bh + gb, &Bhs[buf][grp * 512]);
      gl2lds16(Bl + gb, &Bls[buf][grp * 512]);
    }
  };

  float rmin[4][4];
  int ridx[4][4];
#pragma unroll
  for (int a = 0; a < 4; ++a)
#pragma unroll
    for (int b = 0; b < 4; ++b) { rmin[a][b] = 3.4e38f; ridx[a][b] = 0; }

  // prologue: fill buffer 0 with step 0
  stage(0, 0);
  __syncthreads();   // drains vmcnt -> buf0 ready

  for (int nt = 0; nt < NTILES; ++nt) {
    const int n0 = ns0 + nt * BN;
    f32x4 acc[4][8];
#pragma unroll
    for (int a = 0; a < 4; ++a)
#pragma unroll
      for (int b = 0; b < 8; ++b) {
        f32x4 zz = {0.f, 0.f, 0.f, 0.f};
        acc[a][b] = zz;
      }

#pragma unroll 1
    for (int k8 = 0; k8 < 8; ++k8) {
      const int s = nt * 8 + k8;
      const int cur = s & 1;
      // issue next step's staging FIRST: latency hides under this step's MFMAs
      if (s + 1 < NSTEPS) stage(cur ^ 1, s + 1);

      // ds_read all fragments for this step from buf[cur]
      bf16x8 ah[4], al[4], bh[8], bl[8];
#pragma unroll
      for (int mi = 0; mi < 4; ++mi) {
        const int r = wm * 64 + mi * 16 + l15;
        const int off = r * BK + rd_sw;            // swizzled read
        ah[mi] = *(const bf16x8*)&Ahs[cur][off];
        al[mi] = *(const bf16x8*)&Als[cur][off];
      }
#pragma unroll
      for (int ni = 0; ni < 8; ++ni) {
        const int r = wn * 128 + ni * 16 + l15;
        const int off = r * BK + rd_sw;            // swizzled read
        bh[ni] = *(const bf16x8*)&Bhs[cur][off];
        bl[ni] = *(const bf16x8*)&Bls[cur][off];
      }
      // pass-reordered MFMAs: per-acc order is STILL hh -> hl -> lh
      // (bitwise-identical accumulation), but same-acc dependents are
      // separated by 31 independent MFMAs.
#pragma unroll
      for (int ni = 0; ni < 8; ++ni)
#pragma unroll
        for (int mi = 0; mi < 4; ++mi)
          acc[mi][ni] = __builtin_amdgcn_mfma_f32_16x16x32_bf16(ah[mi], bh[ni], acc[mi][ni], 0, 0, 0);
#pragma unroll
      for (int ni = 0; ni < 8; ++ni)
#pragma unroll
        for (int mi = 0; mi < 4; ++mi)
          acc[mi][ni] = __builtin_amdgcn_mfma_f32_16x16x32_bf16(ah[mi], bl[ni], acc[mi][ni], 0, 0, 0);
#pragma unroll
      for (int ni = 0; ni < 8; ++ni)
#pragma unroll
        for (int mi = 0; mi < 4; ++mi)
          acc[mi][ni] = __builtin_amdgcn_mfma_f32_16x16x32_bf16(al[mi], bh[ni], acc[mi][ni], 0, 0, 0);

      // single barrier per step: completes next-step staging (vmcnt drain,
      // issued ~1900 cyc ago) and retires this step's LDS reads before
      // buf[cur] is overwritten at step s+2.
      __syncthreads();
    }

    // epilogue: dist = (zn + cn) - 2*dot, np op order; cols ascending in ni
    // per (mi,i), so tie-break (strict <, first idx wins) is unchanged.
    float cnv[8];
#pragma unroll
    for (int ni = 0; ni < 8; ++ni)
      cnv[ni] = cnorm[n0 + wn * 128 + ni * 16 + l15];
#pragma unroll
    for (int mi = 0; mi < 4; ++mi) {
      float zr[4];
#pragma unroll
      for (int i = 0; i < 4; ++i)
        zr[i] = znorm[m0 + wm * 64 + mi * 16 + lg * 4 + i];
#pragma unroll
      for (int ni = 0; ni < 8; ++ni) {
        const int col = n0 + wn * 128 + ni * 16 + l15;
        const float cn = cnv[ni];
#pragma unroll
        for (int i = 0; i < 4; ++i) {
          const float s = __fadd_rn(zr[i], cn);
          const float v = __fsub_rn(s, __fmul_rn(2.0f, acc[mi][ni][i]));
          if (v < rmin[mi][i]) { rmin[mi][i] = v; ridx[mi][i] = col; }  // strict <: first idx wins
        }
      }
    }
  }
  // 16-lane butterfly reduce (C/D: col=lane&15, row=(lane>>4)*4+i)
#pragma unroll
  for (int mi = 0; mi < 4; ++mi)
#pragma unroll
    for (int i = 0; i < 4; ++i) {
      float v = rmin[mi][i];
      int ix = ridx[mi][i];
#pragma unroll
      for (int d = 1; d < 16; d <<= 1) {
        float ov = __shfl_xor(v, d);
        int oi = __shfl_xor(ix, d);
        if (ov < v || (ov == v && oi < ix)) { v = ov; ix = oi; }
      }
      if (l15 == 0) {
        const int row = m0 + wm * 64 + mi * 16 + lg * 4 + i;
        const int part = spl * 2 + wn;   // per-(split, wn) slot
        pval[(size_t)part * NQ + row] = v;
        pidx[(size_t)part * NQ + row] = ix;
      }
    }
}

// ---------- K3: combine partials, gather quantized, loss partial ----------
__global__ __launch_bounds__(256) void finalize_kernel(
    const float* __restrict__ pval, const int* __restrict__ pidx,
    const float* __restrict__ qc, const float* __restrict__ z,
    float* __restrict__ out, float* __restrict__ loss_acc) {
  __shared__ int sidx[8];
  __shared__ float red[256];
  const int bid = blockIdx.x;   // 2048 blocks * 8 rows
  const int t = threadIdx.x;
  if (t < 8) {
    const int row = bid * 8 + t;
    float best = pval[row];
    int bi = pidx[row];
    for (int s2 = 1; s2 < NPART; ++s2) {
      float v = pval[(size_t)s2 * NQ + row];
      int ix = pidx[(size_t)s2 * NQ + row];
      if (v < best || (v == best && ix < bi)) { best = v; bi = ix; }
    }
    sidx[t] = bi;
    out[4194305 + row] = (float)bi;   // encoding_indices as f32
  }
  __syncthreads();
  float d2 = 0.f;
#pragma unroll
  for (int r = 0; r < 8; ++r) {
    const int row = bid * 8 + r;
    const int ix = sidx[r];
    const float q = qc[(size_t)ix * 256 + t];
    const float zz = z[(size_t)row * 256 + t];
    out[(size_t)row * 256 + t] = q;   // STE output == quantized value-wise
    const float d = q - zz;
    d2 += d * d;
  }
  red[t] = d2;
  for (int st = 128; st; st >>= 1) {
    __syncthreads();
    if (t < st) red[t] += red[t + st];
  }
  if (t == 0) atomicAdd(loss_acc, red[0]);
}

// ---------- K4: scalar loss write ----------
__global__ void write_loss_kernel(const float* __restrict__ loss_acc, float* __restrict__ out) {
  // commitment_loss == codebook_loss numerically -> vq_loss = 1.25 * mean
  out[4194304] = 1.25f * loss_acc[0] / 4194304.0f;
}

// ---------- launch ----------
extern "C" void kernel_launch(void* const* d_in, const int* in_sizes, int n_in,
                              void* d_out, int out_size, void* d_ws, size_t ws_size,
                              hipStream_t stream) {
  const float* z = (const float*)d_in[0];
  const float* cb = (const float*)d_in[1];
  const float* W = (const float*)d_in[2];
  const float* bias = (const float*)d_in[3];
  float* out = (float*)d_out;
  char* ws = (char*)d_ws;

  constexpr size_t OFF_QC = 0;                      // 16 MB fp32 quant_codebook
  constexpr size_t OFF_AH = OFF_QC + 16777216;      // 8 MB each
  constexpr size_t OFF_AL = OFF_AH + 8388608;
  constexpr size_t OFF_BH = OFF_AL + 8388608;
  constexpr size_t OFF_BL = OFF_BH + 8388608;
  constexpr size_t OFF_CN = OFF_BL + 8388608;       // 64 KB code norms
  constexpr size_t OFF_ZN = OFF_CN + 65536;         // 64 KB query norms
  constexpr size_t OFF_PV = OFF_ZN + 65536;         // 1 MB partial vals (4 sets used)
  constexpr size_t OFF_PI = OFF_PV + 1048576;       // 1 MB partial idx
  constexpr size_t OFF_ACC = OFF_PI + 1048576;      // 4 B loss accumulator

  float* qc = (float*)(ws + OFF_QC);
  u16* Ah = (u16*)(ws + OFF_AH);
  u16* Al = (u16*)(ws + OFF_AL);
  u16* Bh = (u16*)(ws + OFF_BH);
  u16* Bl = (u16*)(ws + OFF_BL);
  float* cn = (float*)(ws + OFF_CN);
  float* zn = (float*)(ws + OFF_ZN);
  float* pv = (float*)(ws + OFF_PV);
  int* pi = (int*)(ws + OFF_PI);
  float* lacc = (float*)(ws + OFF_ACC);

  hipMemsetAsync(lacc, 0, 4, stream);
  split_z_kernel<<<4096, 256, 0, stream>>>(z, Ah, Al);
  qc_gemm_kernel<<<1024, 256, 0, stream>>>(cb, W, bias, qc);
  norm256_kernel<<<NQ / 32, 256, 0, stream>>>(z, zn);
  norm256_kernel<<<NC / 32, 256, 0, stream>>>(qc, cn);
  split_qc_kernel<<<4096, 256, 0, stream>>>(qc, Bh, Bl);
  vq_argmin_kernel<<<(NQ / BM) * NSPLIT, 256, 0, stream>>>(Ah, Al, Bh, Bl, cn, zn, pv, pi);
  finalize_kernel<<<NQ / 8, 256, 0, stream>>>(pv, pi, qc, z, out, lacc);
  write_loss_kernel<<<1, 1, 0, stream>>>(lacc, out);
}

// Round 5
// 584.450 us; speedup vs baseline: 1.1650x; 1.1650x over previous
//
#include <hip/hip_runtime.h>

typedef unsigned short u16;
typedef __bf16 bf16x8 __attribute__((ext_vector_type(8)));
typedef float f32x4 __attribute__((ext_vector_type(4)));

#define NQ 16384       // queries (8*2048)
#define NC 16384       // codes
#define DD 256         // embed dim
#define BM 128         // block tile M (queries)
#define BN 128         // block tile N (codes)
#define BK 32          // k-step
#define NSPLIT 4
#define NPART (NSPLIT * 2)            // 8: per-(split, wn) partials
#define NTILES ((NC / NSPLIT) / BN)   // 32
#define NSTEPS (NTILES * 8)           // 256 flattened (nt, kc) steps

// ---------- fp32 -> bf16 hi/lo split (RNE) ----------
__device__ __forceinline__ u16 f2bf(float x) {
  unsigned u = __float_as_uint(x);
  u += 0x7fffu + ((u >> 16) & 1u);
  return (u16)(u >> 16);
}
__device__ __forceinline__ float bf2f(u16 h) {
  return __uint_as_float(((unsigned)h) << 16);
}

// async global->LDS, 16B per lane; LDS dest is wave-uniform base + lane*16
__device__ __forceinline__ void gl2lds16(const void* g, void* l) {
  __builtin_amdgcn_global_load_lds((__attribute__((address_space(1))) void*)g,
                                   (__attribute__((address_space(3))) void*)l,
                                   16, 0, 0);
}

// ---------- K0: split z into bf16 hi/lo ----------
__global__ __launch_bounds__(256) void split_z_kernel(const float* __restrict__ z,
                                                      u16* __restrict__ Ah,
                                                      u16* __restrict__ Al) {
  size_t i = (size_t)blockIdx.x * 256 + threadIdx.x;   // float4 index
  float4 v = ((const float4*)z)[i];
  float f[4] = {v.x, v.y, v.z, v.w};
  u16 hh[4], ll[4];
#pragma unroll
  for (int j = 0; j < 4; ++j) {
    hh[j] = f2bf(f[j]);
    ll[j] = f2bf(f[j] - bf2f(hh[j]));
  }
  ushort4 h; h.x = hh[0]; h.y = hh[1]; h.z = hh[2]; h.w = hh[3];
  ushort4 l; l.x = ll[0]; l.y = ll[1]; l.z = ll[2]; l.w = ll[3];
  ((ushort4*)Ah)[i] = h;
  ((ushort4*)Al)[i] = l;
}

// ---------- K0b: row norms in EXACT numpy pairwise order ----------
// np.sum(x*x) len-256: two 128-halves; each half: 8 accumulators
// r[j] = sum_{i step 8} x[i+j]^2, combined ((r0+r1)+(r2+r3))+((r4+r5)+(r6+r7));
// total = half0 + half1. Here j -> lane (8 lanes per row, coalesced 32B loads),
// tree combine via shfl_xor in the identical order. Bitwise == old kernel.
__global__ __launch_bounds__(256) void norm256_kernel(const float* __restrict__ x,
                                                      float* __restrict__ nrm) {
  const int t = threadIdx.x;
  const int j = t & 7;                    // accumulator index within row
  const int row = blockIdx.x * 32 + (t >> 3);
  const float* q = x + (size_t)row * 256;
  float half[2];
#pragma unroll
  for (int h = 0; h < 2; ++h) {
    const float* p = q + h * 128;
    float v0 = p[j];
    float r = __fmul_rn(v0, v0);
#pragma unroll
    for (int i = 8; i < 128; i += 8) {
      float v = p[i + j];
      r = __fadd_rn(r, __fmul_rn(v, v));
    }
    float s1 = __fadd_rn(r, __shfl_xor(r, 1));    // r0+r1 | r2+r3 | ...
    float s2 = __fadd_rn(s1, __shfl_xor(s1, 2));  // (r0+r1)+(r2+r3) | ...
    half[h] = __fadd_rn(s2, __shfl_xor(s2, 4));   // full 8-way, np tree order
  }
  if (j == 0) nrm[row] = __fadd_rn(half[0], half[1]);
}

// ---------- K1: qc = cb @ W^T + bias  (fp32, 64x64 tiles) ----------
// DO NOT change numerics here: dist rounding grid depends on qc bits, and this
// exact configuration produced zero index flips vs the np reference.
__global__ __launch_bounds__(256) void qc_gemm_kernel(const float* __restrict__ cb,
                                                      const float* __restrict__ W,
                                                      const float* __restrict__ bias,
                                                      float* __restrict__ qc) {
  __shared__ float As[64][33];
  __shared__ float Bs[64][33];
  const int bm = blockIdx.x >> 2;   // 256 row tiles
  const int bn = blockIdx.x & 3;    // 4 col tiles
  const int m0 = bm * 64, n0 = bn * 64;
  const int t = threadIdx.x;
  const int tx = t & 15, ty = t >> 4;
  float acc[4][4] = {};
  for (int kc = 0; kc < 256; kc += 32) {
    __syncthreads();
#pragma unroll
    for (int j = 0; j < 8; ++j) {
      int idx = j * 256 + t;            // 0..2047
      int r = idx >> 5, c = idx & 31;
      As[r][c] = cb[(size_t)(m0 + r) * 256 + kc + c];
      Bs[r][c] = W[(size_t)(n0 + r) * 256 + kc + c];
    }
    __syncthreads();
#pragma unroll
    for (int kk = 0; kk < 32; ++kk) {
      float a[4], b[4];
#pragma unroll
      for (int u = 0; u < 4; ++u) a[u] = As[ty * 4 + u][kk];
#pragma unroll
      for (int v = 0; v < 4; ++v) b[v] = Bs[tx * 4 + v][kk];
#pragma unroll
      for (int u = 0; u < 4; ++u)
#pragma unroll
        for (int v = 0; v < 4; ++v) acc[u][v] += a[u] * b[v];
    }
  }
#pragma unroll
  for (int u = 0; u < 4; ++u)
#pragma unroll
    for (int v = 0; v < 4; ++v) {
      int r = m0 + ty * 4 + u, c = n0 + tx * 4 + v;
      qc[(size_t)r * 256 + c] = acc[u][v] + bias[c];
    }
}

// ---------- K1b: per-row bf16 hi/lo split of qc ----------
__global__ __launch_bounds__(256) void split_qc_kernel(const float* __restrict__ qc,
                                                       u16* __restrict__ Bh,
                                                       u16* __restrict__ Bl) {
  size_t i = (size_t)blockIdx.x * 256 + threadIdx.x;   // float4 index
  float4 v = ((const float4*)qc)[i];
  float f[4] = {v.x, v.y, v.z, v.w};
  u16 hh[4], ll[4];
#pragma unroll
  for (int j = 0; j < 4; ++j) {
    hh[j] = f2bf(f[j]);
    ll[j] = f2bf(f[j] - bf2f(hh[j]));
  }
  ushort4 h; h.x = hh[0]; h.y = hh[1]; h.z = hh[2]; h.w = hh[3];
  ushort4 l; l.x = ll[0]; l.y = ll[1]; l.z = ll[2]; l.w = ll[3];
  ((ushort4*)Bh)[i] = h;
  ((ushort4*)Bl)[i] = l;
}

// ---------- K2: fused split-bf16 distance GEMM + argmin ----------
// STRUCTURE (round 5): round-0's proven register geometry (128x128 block,
// 4 waves of 64x64, acc[4][4] -- VGPR=128, zero spill) + round-4's proven
// 2-phase pipeline (flattened steps, double-buffered LDS, stage s+1 BEFORE
// computing s, ONE barrier/step), now with BK=32 so LDS = 64 KB -> 2
// blocks/CU (8 waves/CU). Round 4's regression isolated the failure to
// 1 wave/SIMD (MfmaUtil 32%, no TLP to hide ds_read latency + barrier);
// cross-block overlap restores it. Corrected budget (m06: 16x16x32 MFMA
// ~4.85 cyc/CU): per CU per step MFMA 1863 cyc vs LDS 512+256 cyc ->
// MFMA-bound with 2.6x headroom; prefetch distance ~930 cyc covers L2.
// MFMA passes reordered (all hh, all hl, all lh): per-acc order is STILL
// hh->hl->lh over ascending k-chunks -> bitwise-identical (HW-verified in
// round 4). Epilogue ops, tie-break, scan order unchanged.
//
// LDS rows are 32 elems = 4 chunks of 16B. XOR swizzle: position p of row r
// holds logical chunk p ^ ((r>>1)&3). Staging permutes the per-lane GLOBAL
// address (global_load_lds dest must stay linear); reads apply the same XOR.
// 8 lanes per 16B-granule, uniform over all 32 banks = conflict-free
// (measured 0 in all rounds).
__global__ __launch_bounds__(256, 2) void vq_argmin_kernel(
    const u16* __restrict__ Ah, const u16* __restrict__ Al,
    const u16* __restrict__ Bh, const u16* __restrict__ Bl,
    const float* __restrict__ cnorm, const float* __restrict__ znorm,
    float* __restrict__ pval, int* __restrict__ pidx) {
  __shared__ __align__(16) u16 Ahs[2][BM * BK];   // 2 x 8 KiB
  __shared__ __align__(16) u16 Als[2][BM * BK];   // 2 x 8 KiB
  __shared__ __align__(16) u16 Bhs[2][BN * BK];   // 2 x 8 KiB
  __shared__ __align__(16) u16 Bls[2][BN * BK];   // 2 x 8 KiB  => 64 KiB

  const int bm = blockIdx.x / NSPLIT;
  const int spl = blockIdx.x % NSPLIT;
  const int lane = threadIdx.x & 63;
  const int wid = threadIdx.x >> 6;
  const int wm = wid >> 1, wn = wid & 1;     // 2x2 wave grid, 64x64 each
  const int l15 = lane & 15;
  const int lg = lane >> 4;                  // 0..3
  const int m0 = bm * BM;
  const int ns0 = spl * (NC / NSPLIT);

  // staging: lane covers (row = sweep*16 + (lane>>2), lds chunk = lane&3);
  // global k-chunk = (lane&3) ^ s(r) with s(r) = (r>>1)&3 = (lane>>3)&3
  const int st_r = lane >> 2;                               // row within 16-row sweep
  const int st_k = (((lane & 3) ^ ((lane >> 3) & 3)) << 3); // SWIZZLED k elem offset

  // read side: logical chunk lg lives at position lg ^ ((l15>>1)&3)
  const int rd_sw = ((lg ^ ((l15 >> 1) & 3)) << 3);         // elem offset within row

  // stage flattened step s into buffer buf (nt = s>>3, kc = (s&7)*BK)
  // A: 128 rows = 8 sweeps of 16 rows (1024B each); 2 per wave. B: same.
  auto stage = [&](int buf, int s) {
    const int ntt = s >> 3;
    const int kcc = (s & 7) * BK;
    const int nn0 = ns0 + ntt * BN;
#pragma unroll
    for (int j = 0; j < 2; ++j) {
      const int grp = wid * 2 + j;               // 0..7
      const int r = grp * 16 + st_r;             // 0..127
      const size_t ga = (size_t)(m0 + r) * DD + kcc + st_k;
      const size_t gb = (size_t)(nn0 + r) * DD + kcc + st_k;
      gl2lds16(Ah + ga, &Ahs[buf][grp * 512]);
      gl2lds16(Al + ga, &Als[buf][grp * 512]);
      gl2lds16(Bh + gb, &Bhs[buf][grp * 512]);
      gl2lds16(Bl + gb, &Bls[buf][grp * 512]);
    }
  };

  float rmin[4][4];
  int ridx[4][4];
#pragma unroll
  for (int a = 0; a < 4; ++a)
#pragma unroll
    for (int b = 0; b < 4; ++b) { rmin[a][b] = 3.4e38f; ridx[a][b] = 0; }

  // prologue: fill buffer 0 with step 0
  stage(0, 0);
  __syncthreads();   // drains vmcnt -> buf0 ready

  for (int nt = 0; nt < NTILES; ++nt) {
    const int n0 = ns0 + nt * BN;
    f32x4 acc[4][4];
#pragma unroll
    for (int a = 0; a < 4; ++a)
#pragma unroll
      for (int b = 0; b < 4; ++b) {
        f32x4 zz = {0.f, 0.f, 0.f, 0.f};
        acc[a][b] = zz;
      }

#pragma unroll 1
    for (int k8 = 0; k8 < 8; ++k8) {
      const int s = nt * 8 + k8;
      const int cur = s & 1;
      // issue next step's staging FIRST: latency hides under this step's MFMAs
      if (s + 1 < NSTEPS) stage(cur ^ 1, s + 1);

      // ds_read all fragments for this step from buf[cur]
      bf16x8 ah[4], al[4], bh[4], bl[4];
#pragma unroll
      for (int mi = 0; mi < 4; ++mi) {
        const int r = wm * 64 + mi * 16 + l15;
        const int off = r * BK + rd_sw;            // swizzled read
        ah[mi] = *(const bf16x8*)&Ahs[cur][off];
        al[mi] = *(const bf16x8*)&Als[cur][off];
      }
#pragma unroll
      for (int ni = 0; ni < 4; ++ni) {
        const int r = wn * 64 + ni * 16 + l15;
        const int off = r * BK + rd_sw;            // swizzled read
        bh[ni] = *(const bf16x8*)&Bhs[cur][off];
        bl[ni] = *(const bf16x8*)&Bls[cur][off];
      }
      // pass-reordered MFMAs: per-acc order is STILL hh -> hl -> lh
      // (bitwise-identical accumulation, HW-verified round 4), but same-acc
      // dependents are separated by 15 independent MFMAs.
#pragma unroll
      for (int ni = 0; ni < 4; ++ni)
#pragma unroll
        for (int mi = 0; mi < 4; ++mi)
          acc[mi][ni] = __builtin_amdgcn_mfma_f32_16x16x32_bf16(ah[mi], bh[ni], acc[mi][ni], 0, 0, 0);
#pragma unroll
      for (int ni = 0; ni < 4; ++ni)
#pragma unroll
        for (int mi = 0; mi < 4; ++mi)
          acc[mi][ni] = __builtin_amdgcn_mfma_f32_16x16x32_bf16(ah[mi], bl[ni], acc[mi][ni], 0, 0, 0);
#pragma unroll
      for (int ni = 0; ni < 4; ++ni)
#pragma unroll
        for (int mi = 0; mi < 4; ++mi)
          acc[mi][ni] = __builtin_amdgcn_mfma_f32_16x16x32_bf16(al[mi], bh[ni], acc[mi][ni], 0, 0, 0);

      // single barrier per step: completes next-step staging (vmcnt drain,
      // issued a full MFMA phase ago) and retires this step's LDS reads
      // before buf[cur] is overwritten at step s+1's staging.
      __syncthreads();
    }

    // epilogue: dist = (zn + cn) - 2*dot, np op order; cols ascending in ni
    // per (mi,i), so tie-break (strict <, first idx wins) is unchanged.
    float cnv[4];
#pragma unroll
    for (int ni = 0; ni < 4; ++ni)
      cnv[ni] = cnorm[n0 + wn * 64 + ni * 16 + l15];
#pragma unroll
    for (int mi = 0; mi < 4; ++mi) {
      float zr[4];
#pragma unroll
      for (int i = 0; i < 4; ++i)
        zr[i] = znorm[m0 + wm * 64 + mi * 16 + lg * 4 + i];
#pragma unroll
      for (int ni = 0; ni < 4; ++ni) {
        const int col = n0 + wn * 64 + ni * 16 + l15;
        const float cn = cnv[ni];
#pragma unroll
        for (int i = 0; i < 4; ++i) {
          const float s = __fadd_rn(zr[i], cn);
          const float v = __fsub_rn(s, __fmul_rn(2.0f, acc[mi][ni][i]));
          if (v < rmin[mi][i]) { rmin[mi][i] = v; ridx[mi][i] = col; }  // strict <: first idx wins
        }
      }
    }
  }
  // 16-lane butterfly reduce (C/D: col=lane&15, row=(lane>>4)*4+i)
#pragma unroll
  for (int mi = 0; mi < 4; ++mi)
#pragma unroll
    for (int i = 0; i < 4; ++i) {
      float v = rmin[mi][i];
      int ix = ridx[mi][i];
#pragma unroll
      for (int d = 1; d < 16; d <<= 1) {
        float ov = __shfl_xor(v, d);
        int oi = __shfl_xor(ix, d);
        if (ov < v || (ov == v && oi < ix)) { v = ov; ix = oi; }
      }
      if (l15 == 0) {
        const int row = m0 + wm * 64 + mi * 16 + lg * 4 + i;
        const int part = spl * 2 + wn;   // per-(split, wn) slot
        pval[(size_t)part * NQ + row] = v;
        pidx[(size_t)part * NQ + row] = ix;
      }
    }
}

// ---------- K3: combine partials, gather quantized, loss partial ----------
__global__ __launch_bounds__(256) void finalize_kernel(
    const float* __restrict__ pval, const int* __restrict__ pidx,
    const float* __restrict__ qc, const float* __restrict__ z,
    float* __restrict__ out, float* __restrict__ loss_acc) {
  __shared__ int sidx[8];
  __shared__ float red[256];
  const int bid = blockIdx.x;   // 2048 blocks * 8 rows
  const int t = threadIdx.x;
  if (t < 8) {
    const int row = bid * 8 + t;
    float best = pval[row];
    int bi = pidx[row];
    for (int s2 = 1; s2 < NPART; ++s2) {
      float v = pval[(size_t)s2 * NQ + row];
      int ix = pidx[(size_t)s2 * NQ + row];
      if (v < best || (v == best && ix < bi)) { best = v; bi = ix; }
    }
    sidx[t] = bi;
    out[4194305 + row] = (float)bi;   // encoding_indices as f32
  }
  __syncthreads();
  float d2 = 0.f;
#pragma unroll
  for (int r = 0; r < 8; ++r) {
    const int row = bid * 8 + r;
    const int ix = sidx[r];
    const float q = qc[(size_t)ix * 256 + t];
    const float zz = z[(size_t)row * 256 + t];
    out[(size_t)row * 256 + t] = q;   // STE output == quantized value-wise
    const float d = q - zz;
    d2 += d * d;
  }
  red[t] = d2;
  for (int st = 128; st; st >>= 1) {
    __syncthreads();
    if (t < st) red[t] += red[t + st];
  }
  if (t == 0) atomicAdd(loss_acc, red[0]);
}

// ---------- K4: scalar loss write ----------
__global__ void write_loss_kernel(const float* __restrict__ loss_acc, float* __restrict__ out) {
  // commitment_loss == codebook_loss numerically -> vq_loss = 1.25 * mean
  out[4194304] = 1.25f * loss_acc[0] / 4194304.0f;
}

// ---------- launch ----------
extern "C" void kernel_launch(void* const* d_in, const int* in_sizes, int n_in,
                              void* d_out, int out_size, void* d_ws, size_t ws_size,
                              hipStream_t stream) {
  const float* z = (const float*)d_in[0];
  const float* cb = (const float*)d_in[1];
  const float* W = (const float*)d_in[2];
  const float* bias = (const float*)d_in[3];
  float* out = (float*)d_out;
  char* ws = (char*)d_ws;

  constexpr size_t OFF_QC = 0;                      // 16 MB fp32 quant_codebook
  constexpr size_t OFF_AH = OFF_QC + 16777216;      // 8 MB each
  constexpr size_t OFF_AL = OFF_AH + 8388608;
  constexpr size_t OFF_BH = OFF_AL + 8388608;
  constexpr size_t OFF_BL = OFF_BH + 8388608;
  constexpr size_t OFF_CN = OFF_BL + 8388608;       // 64 KB code norms
  constexpr size_t OFF_ZN = OFF_CN + 65536;         // 64 KB query norms
  constexpr size_t OFF_PV = OFF_ZN + 65536;         // 1 MB partial vals (8 sets used)
  constexpr size_t OFF_PI = OFF_PV + 1048576;       // 1 MB partial idx
  constexpr size_t OFF_ACC = OFF_PI + 1048576;      // 4 B loss accumulator

  float* qc = (float*)(ws + OFF_QC);
  u16* Ah = (u16*)(ws + OFF_AH);
  u16* Al = (u16*)(ws + OFF_AL);
  u16* Bh = (u16*)(ws + OFF_BH);
  u16* Bl = (u16*)(ws + OFF_BL);
  float* cn = (float*)(ws + OFF_CN);
  float* zn = (float*)(ws + OFF_ZN);
  float* pv = (float*)(ws + OFF_PV);
  int* pi = (int*)(ws + OFF_PI);
  float* lacc = (float*)(ws + OFF_ACC);

  hipMemsetAsync(lacc, 0, 4, stream);
  split_z_kernel<<<4096, 256, 0, stream>>>(z, Ah, Al);
  qc_gemm_kernel<<<1024, 256, 0, stream>>>(cb, W, bias, qc);
  norm256_kernel<<<NQ / 32, 256, 0, stream>>>(z, zn);
  norm256_kernel<<<NC / 32, 256, 0, stream>>>(qc, cn);
  split_qc_kernel<<<4096, 256, 0, stream>>>(qc, Bh, Bl);
  vq_argmin_kernel<<<(NQ / BM) * NSPLIT, 256, 0, stream>>>(Ah, Al, Bh, Bl, cn, zn, pv, pi);
  finalize_kernel<<<NQ / 8, 256, 0, stream>>>(pv, pi, qc, z, out, lacc);
  write_loss_kernel<<<1, 1, 0, stream>>>(lacc, out);
}

// Round 6
// 529.673 us; speedup vs baseline: 1.2855x; 1.1034x over previous
//
#include <hip/hip_runtime.h>

typedef unsigned short u16;
typedef __bf16 bf16x8 __attribute__((ext_vector_type(8)));
typedef float f32x4 __attribute__((ext_vector_type(4)));

#define NQ 16384       // queries (8*2048)
#define NC 16384       // codes
#define DD 256         // embed dim
#define BM 256         // block tile M (queries)
#define BN 256         // block tile N (codes)
#define BK 32          // k-step
#define NSPLIT 8
#define NPART (NSPLIT * 2)            // 16: per-(split, wn) partials
#define NTILES ((NC / NSPLIT) / BN)   // 8
#define NSTEPS (NTILES * 8)           // 64 flattened (nt, kc) steps

// ---------- fp32 -> bf16 hi/lo split (RNE) ----------
__device__ __forceinline__ u16 f2bf(float x) {
  unsigned u = __float_as_uint(x);
  u += 0x7fffu + ((u >> 16) & 1u);
  return (u16)(u >> 16);
}
__device__ __forceinline__ float bf2f(u16 h) {
  return __uint_as_float(((unsigned)h) << 16);
}

// async global->LDS, 16B per lane; LDS dest is wave-uniform base + lane*16
__device__ __forceinline__ void gl2lds16(const void* g, void* l) {
  __builtin_amdgcn_global_load_lds((__attribute__((address_space(1))) void*)g,
                                   (__attribute__((address_space(3))) void*)l,
                                   16, 0, 0);
}

// MFMA with accumulator FORCED into AGPRs (proven R3/R4: removes the
// allocator's choice that spilled acc to scratch in R1/R2). Dataflow through
// operands still gets correct waitcnt insertion; MFMA->MFMA same-acc
// chaining is the architected accumulate path.
#define MFMA_AGPR(ACC, A, B) \
  asm("v_mfma_f32_16x16x32_bf16 %0, %1, %2, %0" : "+a"(ACC) : "v"(A), "v"(B))

// ---------- K0: split z into bf16 hi/lo ----------
__global__ __launch_bounds__(256) void split_z_kernel(const float* __restrict__ z,
                                                      u16* __restrict__ Ah,
                                                      u16* __restrict__ Al) {
  size_t i = (size_t)blockIdx.x * 256 + threadIdx.x;   // float4 index
  float4 v = ((const float4*)z)[i];
  float f[4] = {v.x, v.y, v.z, v.w};
  u16 hh[4], ll[4];
#pragma unroll
  for (int j = 0; j < 4; ++j) {
    hh[j] = f2bf(f[j]);
    ll[j] = f2bf(f[j] - bf2f(hh[j]));
  }
  ushort4 h; h.x = hh[0]; h.y = hh[1]; h.z = hh[2]; h.w = hh[3];
  ushort4 l; l.x = ll[0]; l.y = ll[1]; l.z = ll[2]; l.w = ll[3];
  ((ushort4*)Ah)[i] = h;
  ((ushort4*)Al)[i] = l;
}

// ---------- K0b: row norms in EXACT numpy pairwise order ----------
__global__ __launch_bounds__(256) void norm256_kernel(const float* __restrict__ x,
                                                      float* __restrict__ nrm) {
  const int t = threadIdx.x;
  const int j = t & 7;                    // accumulator index within row
  const int row = blockIdx.x * 32 + (t >> 3);
  const float* q = x + (size_t)row * 256;
  float half[2];
#pragma unroll
  for (int h = 0; h < 2; ++h) {
    const float* p = q + h * 128;
    float v0 = p[j];
    float r = __fmul_rn(v0, v0);
#pragma unroll
    for (int i = 8; i < 128; i += 8) {
      float v = p[i + j];
      r = __fadd_rn(r, __fmul_rn(v, v));
    }
    float s1 = __fadd_rn(r, __shfl_xor(r, 1));    // r0+r1 | r2+r3 | ...
    float s2 = __fadd_rn(s1, __shfl_xor(s1, 2));  // (r0+r1)+(r2+r3) | ...
    half[h] = __fadd_rn(s2, __shfl_xor(s2, 4));   // full 8-way, np tree order
  }
  if (j == 0) nrm[row] = __fadd_rn(half[0], half[1]);
}

// ---------- K1: qc = cb @ W^T + bias  (fp32, 64x64 tiles) ----------
// DO NOT change numerics here: dist rounding grid depends on qc bits.
__global__ __launch_bounds__(256) void qc_gemm_kernel(const float* __restrict__ cb,
                                                      const float* __restrict__ W,
                                                      const float* __restrict__ bias,
                                                      float* __restrict__ qc) {
  __shared__ float As[64][33];
  __shared__ float Bs[64][33];
  const int bm = blockIdx.x >> 2;   // 256 row tiles
  const int bn = blockIdx.x & 3;    // 4 col tiles
  const int m0 = bm * 64, n0 = bn * 64;
  const int t = threadIdx.x;
  const int tx = t & 15, ty = t >> 4;
  float acc[4][4] = {};
  for (int kc = 0; kc < 256; kc += 32) {
    __syncthreads();
#pragma unroll
    for (int j = 0; j < 8; ++j) {
      int idx = j * 256 + t;            // 0..2047
      int r = idx >> 5, c = idx & 31;
      As[r][c] = cb[(size_t)(m0 + r) * 256 + kc + c];
      Bs[r][c] = W[(size_t)(n0 + r) * 256 + kc + c];
    }
    __syncthreads();
#pragma unroll
    for (int kk = 0; kk < 32; ++kk) {
      float a[4], b[4];
#pragma unroll
      for (int u = 0; u < 4; ++u) a[u] = As[ty * 4 + u][kk];
#pragma unroll
      for (int v = 0; v < 4; ++v) b[v] = Bs[tx * 4 + v][kk];
#pragma unroll
      for (int u = 0; u < 4; ++u)
#pragma unroll
        for (int v = 0; v < 4; ++v) acc[u][v] += a[u] * b[v];
    }
  }
#pragma unroll
  for (int u = 0; u < 4; ++u)
#pragma unroll
    for (int v = 0; v < 4; ++v) {
      int r = m0 + ty * 4 + u, c = n0 + tx * 4 + v;
      qc[(size_t)r * 256 + c] = acc[u][v] + bias[c];
    }
}

// ---------- K1b: per-row bf16 hi/lo split of qc ----------
__global__ __launch_bounds__(256) void split_qc_kernel(const float* __restrict__ qc,
                                                       u16* __restrict__ Bh,
                                                       u16* __restrict__ Bl) {
  size_t i = (size_t)blockIdx.x * 256 + threadIdx.x;   // float4 index
  float4 v = ((const float4*)qc)[i];
  float f[4] = {v.x, v.y, v.z, v.w};
  u16 hh[4], ll[4];
#pragma unroll
  for (int j = 0; j < 4; ++j) {
    hh[j] = f2bf(f[j]);
    ll[j] = f2bf(f[j] - bf2f(hh[j]));
  }
  ushort4 h; h.x = hh[0]; h.y = hh[1]; h.z = hh[2]; h.w = hh[3];
  ushort4 l; l.x = ll[0]; l.y = ll[1]; l.z = ll[2]; l.w = ll[3];
  ((ushort4*)Bh)[i] = h;
  ((ushort4*)Bl)[i] = l;
}

// ---------- K2: fused split-bf16 distance GEMM + argmin ----------
// ROUND 6 STRUCTURE. R0/R5 triangulated the plateau: not spill (R5 clean),
// not conflicts (0), but FETCH 1.08 GB (34x over ideal 32 MB) -> staging
// loads see loaded-cache latencies that a 1-step vmcnt(0) drain can't hide.
// Changes:
//  (1) 256x256 block (512 thr, 8 waves 4Mx2N): gross staged 16 -> 8 B/output;
//      NSPLIT=8 makes blockIdx%8 = spl = XCD -> each XCD's 4MB B-partition
//      is L2-resident.
//  (2) wave tile 64x128, acc[4][8] asm-AGPR (R3-proven): ds_read per MFMA
//      x0.75; LDS-port 2560 cyc < MFMA 3725 cyc per CU-step.
//  (3) counted vmcnt, never 0 in main loop (T4): per step
//      B_a -> issue stage(s+1) -> vmcnt(8) (retires stage(s), in-order
//      VMEM retirement) -> B_b -> reads+MFMA. B_a separates step-(s-1)
//      reads of buf^1 from stage(s+1) writes; B_b publishes stage(s) after
//      each wave's own vmcnt(8). Same barrier density as R0, no drains.
// VGPR budget at launch_bounds(512,2) (256 regs/wave): acc 128 AGPR +
// arch VGPRs ah/al 32 + B-quad 32 (quad-split + sched_barrier caps
// liveness, R2 pattern) + rmin/ridx 32 + addr ~25 <= 128.
// Numerics: same MFMA, same per-acc hh->hl->lh order over the same 8
// ascending k-chunks, same epilogue ops, columns ascending per lane ->
// bitwise-identical dists and argmin indices.
//
// LDS rows are 32 elems = 4 chunks of 16B. XOR swizzle: position p of row r
// holds logical chunk p ^ ((r>>1)&3). Staging permutes the per-lane GLOBAL
// address (global_load_lds dest must stay linear); reads apply the same XOR.
// 8 lanes per 16B-granule = conflict-free (measured 0 in all rounds).
__global__ __launch_bounds__(512, 2) void vq_argmin_kernel(
    const u16* __restrict__ Ah, const u16* __restrict__ Al,
    const u16* __restrict__ Bh, const u16* __restrict__ Bl,
    const float* __restrict__ cnorm, const float* __restrict__ znorm,
    float* __restrict__ pval, int* __restrict__ pidx) {
  __shared__ __align__(16) u16 Ahs[2][BM * BK];   // 2 x 16 KiB
  __shared__ __align__(16) u16 Als[2][BM * BK];   // 2 x 16 KiB
  __shared__ __align__(16) u16 Bhs[2][BN * BK];   // 2 x 16 KiB
  __shared__ __align__(16) u16 Bls[2][BN * BK];   // 2 x 16 KiB  => 128 KiB

  const int bm = blockIdx.x / NSPLIT;
  const int spl = blockIdx.x % NSPLIT;   // == XCD id (blockIdx round-robin)
  const int lane = threadIdx.x & 63;
  const int wid = threadIdx.x >> 6;      // 0..7
  const int wm = wid >> 1, wn = wid & 1; // 4x2 wave grid, 64x128 each
  const int l15 = lane & 15;
  const int lg = lane >> 4;              // 0..3
  const int m0 = bm * BM;
  const int ns0 = spl * (NC / NSPLIT);

  // staging: lane covers (row = sweep*16 + (lane>>2), lds chunk = lane&3);
  // global k-chunk = (lane&3) ^ s(r) with s(r) = (r>>1)&3 = (lane>>3)&3
  const int st_r = lane >> 2;                               // row within 16-row sweep
  const int st_k = (((lane & 3) ^ ((lane >> 3) & 3)) << 3); // SWIZZLED k elem offset

  // read side: logical chunk lg lives at position lg ^ ((l15>>1)&3)
  const int rd_sw = ((lg ^ ((l15 >> 1) & 3)) << 3);         // elem offset within row

  // stage flattened step s (nt = s>>3, kc = (s&7)*BK): 8 loads/thread.
  // A: 256 rows = 16 sweeps of 16 rows (1024B each); 2 per wave. B: same.
  auto stage = [&](int buf, int s) {
    const int ntt = s >> 3;
    const int kcc = (s & 7) * BK;
    const int nn0 = ns0 + ntt * BN;
#pragma unroll
    for (int j = 0; j < 2; ++j) {
      const int grp = wid * 2 + j;               // 0..15
      const int r = grp * 16 + st_r;             // 0..255
      const size_t ga = (size_t)(m0 + r) * DD + kcc + st_k;
      const size_t gb = (size_t)(nn0 + r) * DD + kcc + st_k;
      gl2lds16(Ah + ga, &Ahs[buf][grp * 512]);
      gl2lds16(Al + ga, &Als[buf][grp * 512]);
      gl2lds16(Bh + gb, &Bhs[buf][grp * 512]);
      gl2lds16(Bl + gb, &Bls[buf][grp * 512]);
    }
  };

  float rmin[4][4];
  int ridx[4][4];
#pragma unroll
  for (int a = 0; a < 4; ++a)
#pragma unroll
    for (int b = 0; b < 4; ++b) { rmin[a][b] = 3.4e38f; ridx[a][b] = 0; }

  // prologue: fill buffer 0 with step 0 (only place vmcnt hits 0 cold)
  stage(0, 0);
  asm volatile("s_waitcnt vmcnt(0)" ::: "memory");
  __builtin_amdgcn_s_barrier();

  for (int nt = 0; nt < NTILES; ++nt) {
    const int n0 = ns0 + nt * BN;
    f32x4 acc[4][8];
#pragma unroll
    for (int a = 0; a < 4; ++a)
#pragma unroll
      for (int b = 0; b < 8; ++b) {
        f32x4 zz = {0.f, 0.f, 0.f, 0.f};
        acc[a][b] = zz;
      }

#pragma unroll 1
    for (int k8 = 0; k8 < 8; ++k8) {
      const int s = nt * 8 + k8;
      const int cur = s & 1;

      // B_a: all waves' reads of buf[cur^1] (step s-1) are retired
      __builtin_amdgcn_s_barrier();
      if (s + 1 < NSTEPS) {
        stage(cur ^ 1, s + 1);                           // 8 new loads
        asm volatile("s_waitcnt vmcnt(8)" ::: "memory"); // retire stage(s)
      } else {
        asm volatile("s_waitcnt vmcnt(0)" ::: "memory"); // last step: drain
      }
      // B_b: everyone's stage(s) writes are visible
      __builtin_amdgcn_s_barrier();
      __builtin_amdgcn_sched_barrier(0);

      bf16x8 ah[4], al[4];
#pragma unroll
      for (int mi = 0; mi < 4; ++mi) {
        const int r = wm * 64 + mi * 16 + l15;
        const int off = r * BK + rd_sw;            // swizzled read
        ah[mi] = *(const bf16x8*)&Ahs[cur][off];
        al[mi] = *(const bf16x8*)&Als[cur][off];
      }
      __builtin_amdgcn_s_setprio(1);
      // ---- quad 0: ni = 0..3 (B frags capped at 32 VGPRs live) ----
      {
        bf16x8 bh[4], bl[4];
#pragma unroll
        for (int nq = 0; nq < 4; ++nq) {
          const int r = wn * 128 + nq * 16 + l15;
          const int off = r * BK + rd_sw;          // swizzled read
          bh[nq] = *(const bf16x8*)&Bhs[cur][off];
          bl[nq] = *(const bf16x8*)&Bls[cur][off];
        }
        // 3 passes; per-acc order hh -> hl -> lh (bitwise-identical)
#pragma unroll
        for (int nq = 0; nq < 4; ++nq)
#pragma unroll
          for (int mi = 0; mi < 4; ++mi)
            MFMA_AGPR(acc[mi][nq], ah[mi], bh[nq]);
#pragma unroll
        for (int nq = 0; nq < 4; ++nq)
#pragma unroll
          for (int mi = 0; mi < 4; ++mi)
            MFMA_AGPR(acc[mi][nq], ah[mi], bl[nq]);
#pragma unroll
        for (int nq = 0; nq < 4; ++nq)
#pragma unroll
          for (int mi = 0; mi < 4; ++mi)
            MFMA_AGPR(acc[mi][nq], al[mi], bh[nq]);
      }
      __builtin_amdgcn_sched_barrier(0);  // do NOT hoist quad-1 B loads
      // ---- quad 1: ni = 4..7 ----
      {
        bf16x8 bh[4], bl[4];
#pragma unroll
        for (int nq = 0; nq < 4; ++nq) {
          const int r = wn * 128 + (4 + nq) * 16 + l15;
          const int off = r * BK + rd_sw;          // swizzled read
          bh[nq] = *(const bf16x8*)&Bhs[cur][off];
          bl[nq] = *(const bf16x8*)&Bls[cur][off];
        }
#pragma unroll
        for (int nq = 0; nq < 4; ++nq)
#pragma unroll
          for (int mi = 0; mi < 4; ++mi)
            MFMA_AGPR(acc[mi][4 + nq], ah[mi], bh[nq]);
#pragma unroll
        for (int nq = 0; nq < 4; ++nq)
#pragma unroll
          for (int mi = 0; mi < 4; ++mi)
            MFMA_AGPR(acc[mi][4 + nq], ah[mi], bl[nq]);
#pragma unroll
        for (int nq = 0; nq < 4; ++nq)
#pragma unroll
          for (int mi = 0; mi < 4; ++mi)
            MFMA_AGPR(acc[mi][4 + nq], al[mi], bh[nq]);
      }
      __builtin_amdgcn_s_setprio(0);
    }

    // epilogue: dist = (zn + cn) - 2*dot, np op order; cols ascending in ni
    // per (mi,i), so tie-break (strict <, first idx wins) is unchanged.
    // (touches no LDS -> safe to overlap other waves' next-step staging)
    float cnv[8];
#pragma unroll
    for (int ni = 0; ni < 8; ++ni)
      cnv[ni] = cnorm[n0 + wn * 128 + ni * 16 + l15];
#pragma unroll
    for (int mi = 0; mi < 4; ++mi) {
      float zr[4];
#pragma unroll
      for (int i = 0; i < 4; ++i)
        zr[i] = znorm[m0 + wm * 64 + mi * 16 + lg * 4 + i];
#pragma unroll
      for (int ni = 0; ni < 8; ++ni) {
        const int col = n0 + wn * 128 + ni * 16 + l15;
        const float cn = cnv[ni];
#pragma unroll
        for (int i = 0; i < 4; ++i) {
          const float s = __fadd_rn(zr[i], cn);
          const float v = __fsub_rn(s, __fmul_rn(2.0f, acc[mi][ni][i]));
          if (v < rmin[mi][i]) { rmin[mi][i] = v; ridx[mi][i] = col; }  // strict <
        }
      }
    }
  }
  // 16-lane butterfly reduce (C/D: col=lane&15, row=(lane>>4)*4+i)
#pragma unroll
  for (int mi = 0; mi < 4; ++mi)
#pragma unroll
    for (int i = 0; i < 4; ++i) {
      float v = rmin[mi][i];
      int ix = ridx[mi][i];
#pragma unroll
      for (int d = 1; d < 16; d <<= 1) {
        float ov = __shfl_xor(v, d);
        int oi = __shfl_xor(ix, d);
        if (ov < v || (ov == v && oi < ix)) { v = ov; ix = oi; }
      }
      if (l15 == 0) {
        const int row = m0 + wm * 64 + mi * 16 + lg * 4 + i;
        const int part = spl * 2 + wn;   // per-(split, wn) slot: 0..15
        pval[(size_t)part * NQ + row] = v;
        pidx[(size_t)part * NQ + row] = ix;
      }
    }
}

// ---------- K3: combine partials, gather quantized, loss partial ----------
__global__ __launch_bounds__(256) void finalize_kernel(
    const float* __restrict__ pval, const int* __restrict__ pidx,
    const float* __restrict__ qc, const float* __restrict__ z,
    float* __restrict__ out, float* __restrict__ loss_acc) {
  __shared__ int sidx[8];
  __shared__ float red[256];
  const int bid = blockIdx.x;   // 2048 blocks * 8 rows
  const int t = threadIdx.x;
  if (t < 8) {
    const int row = bid * 8 + t;
    float best = pval[row];
    int bi = pidx[row];
    for (int s2 = 1; s2 < NPART; ++s2) {
      float v = pval[(size_t)s2 * NQ + row];
      int ix = pidx[(size_t)s2 * NQ + row];
      if (v < best || (v == best && ix < bi)) { best = v; bi = ix; }
    }
    sidx[t] = bi;
    out[4194305 + row] = (float)bi;   // encoding_indices as f32
  }
  __syncthreads();
  float d2 = 0.f;
#pragma unroll
  for (int r = 0; r < 8; ++r) {
    const int row = bid * 8 + r;
    const int ix = sidx[r];
    const float q = qc[(size_t)ix * 256 + t];
    const float zz = z[(size_t)row * 256 + t];
    out[(size_t)row * 256 + t] = q;   // STE output == quantized value-wise
    const float d = q - zz;
    d2 += d * d;
  }
  red[t] = d2;
  for (int st = 128; st; st >>= 1) {
    __syncthreads();
    if (t < st) red[t] += red[t + st];
  }
  if (t == 0) atomicAdd(loss_acc, red[0]);
}

// ---------- K4: scalar loss write ----------
__global__ void write_loss_kernel(const float* __restrict__ loss_acc, float* __restrict__ out) {
  // commitment_loss == codebook_loss numerically -> vq_loss = 1.25 * mean
  out[4194304] = 1.25f * loss_acc[0] / 4194304.0f;
}

// ---------- launch ----------
extern "C" void kernel_launch(void* const* d_in, const int* in_sizes, int n_in,
                              void* d_out, int out_size, void* d_ws, size_t ws_size,
                              hipStream_t stream) {
  const float* z = (const float*)d_in[0];
  const float* cb = (const float*)d_in[1];
  const float* W = (const float*)d_in[2];
  const float* bias = (const float*)d_in[3];
  float* out = (float*)d_out;
  char* ws = (char*)d_ws;

  constexpr size_t OFF_QC = 0;                      // 16 MB fp32 quant_codebook
  constexpr size_t OFF_AH = OFF_QC + 16777216;      // 8 MB each
  constexpr size_t OFF_AL = OFF_AH + 8388608;
  constexpr size_t OFF_BH = OFF_AL + 8388608;
  constexpr size_t OFF_BL = OFF_BH + 8388608;
  constexpr size_t OFF_CN = OFF_BL + 8388608;       // 64 KB code norms
  constexpr size_t OFF_ZN = OFF_CN + 65536;         // 64 KB query norms
  constexpr size_t OFF_PV = OFF_ZN + 65536;         // 1 MB partial vals (16 sets)
  constexpr size_t OFF_PI = OFF_PV + 1048576;       // 1 MB partial idx
  constexpr size_t OFF_ACC = OFF_PI + 1048576;      // 4 B loss accumulator

  float* qc = (float*)(ws + OFF_QC);
  u16* Ah = (u16*)(ws + OFF_AH);
  u16* Al = (u16*)(ws + OFF_AL);
  u16* Bh = (u16*)(ws + OFF_BH);
  u16* Bl = (u16*)(ws + OFF_BL);
  float* cn = (float*)(ws + OFF_CN);
  float* zn = (float*)(ws + OFF_ZN);
  float* pv = (float*)(ws + OFF_PV);
  int* pi = (int*)(ws + OFF_PI);
  float* lacc = (float*)(ws + OFF_ACC);

  hipMemsetAsync(lacc, 0, 4, stream);
  split_z_kernel<<<4096, 256, 0, stream>>>(z, Ah, Al);
  qc_gemm_kernel<<<1024, 256, 0, stream>>>(cb, W, bias, qc);
  norm256_kernel<<<NQ / 32, 256, 0, stream>>>(z, zn);
  norm256_kernel<<<NC / 32, 256, 0, stream>>>(qc, cn);
  split_qc_kernel<<<4096, 256, 0, stream>>>(qc, Bh, Bl);
  vq_argmin_kernel<<<(NQ / BM) * NSPLIT, 512, 0, stream>>>(Ah, Al, Bh, Bl, cn, zn, pv, pi);
  finalize_kernel<<<NQ / 8, 256, 0, stream>>>(pv, pi, qc, z, out, lacc);
  write_loss_kernel<<<1, 1, 0, stream>>>(lacc, out);
}